// Round 9
// baseline (5962.262 us; speedup 1.0000x reference)
//
#include <hip/hip_runtime.h>
#include <stdint.h>

#define TS   1024
#define NB   32
#define DIN  512
#define HU   768
#define NWG  32          // workgroups per direction
#define UPW  24          // hidden units per WG
#define XPAD 520         // x LDS row stride in fp16 (16B-aligned rows)
#define HPAD 772         // h LDS row stride in fp16 (row=1544B -> 2-way banks on reads)
#define SPIN_MAX 16384

typedef _Float16 f16x8 __attribute__((ext_vector_type(8)));
typedef float f32x16 __attribute__((ext_vector_type(16)));
typedef unsigned int u32;
typedef unsigned long long u64;
typedef u32 u32x4 __attribute__((ext_vector_type(4)));

__device__ __forceinline__ u32 f2h_bits(float f) {
  _Float16 h = (_Float16)f;
  return (u32)__builtin_bit_cast(unsigned short, h);
}

// ---- init: zero 2 dirs x 2 slots x 8192 u64 (tag 0 == step-0 ready; replay-safe) ----
__global__ void lstm_init_k(u64* hb) {
  hb[blockIdx.x * 256 + threadIdx.x] = 0ull;   // 128 x 256 = 32768 u64 = 256 KB
}

// ---- transpose + fp16 convert: x[B][T][D] -> xh[T][B][D] ----
__global__ void lstm_xpose_k(const float* __restrict__ x, unsigned short* __restrict__ xh) {
  int idx = blockIdx.x * 256 + threadIdx.x;
  int d4 = idx & 127;
  int t  = (idx >> 7) & 1023;
  int b  = idx >> 17;
  float4 v = *(const float4*)(x + ((size_t)(b * TS + t) * DIN + d4 * 4));
  ushort4 o;
  o.x = (unsigned short)f2h_bits(v.x); o.y = (unsigned short)f2h_bits(v.y);
  o.z = (unsigned short)f2h_bits(v.z); o.w = (unsigned short)f2h_bits(v.w);
  *(ushort4*)(xh + ((size_t)(t * NB + b) * DIN + d4 * 4)) = o;
}

#define BAR_LGKM() do { asm volatile("s_waitcnt lgkmcnt(0)" ::: "memory"); \
  __builtin_amdgcn_sched_barrier(0); __builtin_amdgcn_s_barrier(); \
  __builtin_amdgcn_sched_barrier(0); } while (0)

// ---- persistent bidirectional LSTM scan (64 blocks, tagged-word sync) ----
__global__ __launch_bounds__(256, 1) void lstm_persist_k(
    const float* __restrict__ Wfw, const float* __restrict__ bfw, const float* __restrict__ pfw,
    const float* __restrict__ Wbw, const float* __restrict__ bbw, const float* __restrict__ pbw,
    const unsigned short* __restrict__ xh,
    u64* hb, float* __restrict__ out)
{
  __shared__ __align__(16) unsigned short As[NB * XPAD];   // 33,280 B (x tile)
  __shared__ __align__(16) unsigned short Hs[NB * HPAD];   // 49,408 B (h tile)
  __shared__ __align__(16) float Zs[4][NB][100];           // 51,200 B

  const int tid = threadIdx.x;
  const int dir = (blockIdx.x >= NWG) ? 1 : 0;
  const int gg  = blockIdx.x & (NWG - 1);

  const float* W    = dir ? Wbw : Wfw;
  const float* bias = dir ? bbw : bfw;
  const float* peep = dir ? pbw : pfw;
  u64* hslot = hb + (size_t)dir * 2 * 8192;   // [2 slots][8192 u64]
  const int u0 = gg * UPW;

  const int lane  = tid & 63;
  const int wq    = tid >> 6;      // wave id
  const int colc  = lane & 31;
  const int khalf = lane >> 5;
  const int arow  = colc;          // A-frag row = batch
  const int eb    = tid >> 3;      // epilogue batch row
  const int ep    = tid & 7;       // epilogue phase

  // ---- preload W: 3 col-tiles x 20 K-slices; K-stripe c = 8m + 4*khalf + wq ----
  f16x8 wfr[3][20];
#pragma unroll
  for (int ct = 0; ct < 3; ++ct) {
    const int gcol = (colc & 3) * HU + u0 + 8 * ct + (colc >> 2);
#pragma unroll
    for (int m = 0; m < 20; ++m) {
      const int k0 = (8 * m + 4 * khalf + wq) * 8;
#pragma unroll
      for (int j = 0; j < 8; ++j)
        wfr[ct][m][j] = (_Float16)W[(size_t)(k0 + j) * 3072 + gcol];
    }
  }

  // ---- epilogue constants: 3 contiguous units U = u0 + 3*ep + q ----
  float bi[3], bj[3], bfc[3], bo[3], pi[3], pfc[3], po[3], cst[3];
#pragma unroll
  for (int q = 0; q < 3; ++q) {
    const int U = u0 + 3 * ep + q;
    bi[q] = bias[U]; bj[q] = bias[HU + U]; bfc[q] = bias[2 * HU + U]; bo[q] = bias[3 * HU + U];
    pi[q] = peep[U]; pfc[q] = peep[HU + U]; po[q] = peep[2 * HU + U];
    cst[q] = 0.0f;
  }

  // ---- prologue: x(t0) -> LDS ----
  {
    const unsigned short* x0 = xh + (size_t)(dir ? (TS - 1) : 0) * (NB * DIN);
    u32x4 t[8];
#pragma unroll
    for (int k = 0; k < 8; ++k) t[k] = *(const u32x4*)(x0 + (tid + 256 * k) * 8);
#pragma unroll
    for (int k = 0; k < 8; ++k) {
      const int idx = tid + 256 * k;
      *(u32x4*)(&As[(idx >> 6) * XPAD + (idx & 63) * 8]) = t[k];
    }
  }
  BAR_LGKM();

  u32x4 xr[8];   // x prefetch regs for step s+1

  for (int s = 0; s < TS; ++s) {
    const int t_in = dir ? (TS - 1 - s) : s;
    const u32 tag = (u32)s;
    const char* hp = (const char*)(hslot + (size_t)(s & 1) * 8192) + 16 * tid;
    u64* hdst = hslot + (size_t)((s + 1) & 1) * 8192;

    // ---- A: issue tagged h(s) loads (lane-stride 16B, fully coalesced, MALL) ----
    u32x4 hw[16];
#pragma unroll
    for (int k = 0; k < 16; ++k)
      asm volatile("global_load_dwordx4 %0, %1, off sc0 sc1"
                   : "=v"(hw[k]) : "v"(hp + 4096 * k) : "memory");

    // ---- A2: x(s+1) prefetch (plain cached) — overlaps the same round trip ----
    if (s + 1 < TS) {
      const unsigned short* xnb = xh + (size_t)(dir ? (TS - 2 - s) : (s + 1)) * (NB * DIN);
#pragma unroll
      for (int k = 0; k < 8; ++k) xr[k] = *(const u32x4*)(xnb + (tid + 256 * k) * 8);
    }

    // ---- B: x-tile MFMAs (LDS, staged last step) fill the latency shadow ----
    f32x16 a0, a1, a2;
#pragma unroll
    for (int r = 0; r < 16; ++r) { a0[r] = 0.f; a1[r] = 0.f; a2[r] = 0.f; }
#pragma unroll
    for (int m = 0; m < 8; ++m) {
      const int c = 8 * m + 4 * khalf + wq;
      const f16x8 av = *(const f16x8*)(&As[arow * XPAD + c * 8]);
      a0 = __builtin_amdgcn_mfma_f32_32x32x16_f16(av, wfr[0][m], a0, 0, 0, 0);
      a1 = __builtin_amdgcn_mfma_f32_32x32x16_f16(av, wfr[1][m], a1, 0, 0, 0);
      a2 = __builtin_amdgcn_mfma_f32_32x32x16_f16(av, wfr[2][m], a2, 0, 0, 0);
    }

    // ---- C: tag check + bounded retry (all waits are load-RT only: out stores
    //      are L2-acked plain stores issued a full compute-phase earlier) ----
    {
      int it = 0;
      while (true) {
        asm volatile("s_waitcnt vmcnt(0)" ::: "memory");
        __builtin_amdgcn_sched_barrier(0);
        u32 bad = 0;
#pragma unroll
        for (int k = 0; k < 16; ++k)
          bad |= ((hw[k][1] >> 16) ^ tag) | ((hw[k][3] >> 16) ^ tag);
        if (__all((int)(bad == 0)) || ++it >= SPIN_MAX) break;
        if (it > 64) __builtin_amdgcn_s_sleep(1);
#pragma unroll
        for (int k = 0; k < 16; ++k)
          asm volatile("global_load_dwordx4 %0, %1, off sc0 sc1"
                       : "=v"(hw[k]) : "v"(hp + 4096 * k) : "memory");
      }
    }

    // ---- D: unpack {3 fp16 + tag}x2 per 16B -> Hs ----
    {
      char* dp0 = (char*)Hs + (size_t)(tid >> 7) * (2 * HPAD) + 12 * (tid & 127);
#pragma unroll
      for (int k = 0; k < 16; ++k) {
        const u32 xw = hw[k][0], yw = hw[k][1], zw = hw[k][2], ww = hw[k][3];
        char* dp = dp0 + k * (4 * HPAD);               // 2 rows per k
        *(u32*)(dp)     = xw;
        *(u32*)(dp + 4) = (yw & 0xFFFFu) | (zw << 16);
        *(u32*)(dp + 8) = (zw >> 16) | (ww << 16);
      }
    }
    BAR_LGKM();   // Hs complete; all As x-reads done

    // ---- E: h-tile MFMAs ----
#pragma unroll
    for (int m = 8; m < 20; ++m) {
      const int c = 8 * m + 4 * khalf + wq;
      const f16x8 av = *(const f16x8*)((char*)Hs + arow * (2 * HPAD) + (c - 64) * 16);
      a0 = __builtin_amdgcn_mfma_f32_32x32x16_f16(av, wfr[0][m], a0, 0, 0, 0);
      a1 = __builtin_amdgcn_mfma_f32_32x32x16_f16(av, wfr[1][m], a1, 0, 0, 0);
      a2 = __builtin_amdgcn_mfma_f32_32x32x16_f16(av, wfr[2][m], a2, 0, 0, 0);
    }

    // ---- F: partial z -> LDS; C/D: col=lane&31, row=(r&3)+8*(r>>2)+4*khalf ----
#pragma unroll
    for (int r = 0; r < 16; ++r) {
      const int prow = (r & 3) + 8 * (r >> 2) + 4 * khalf;
      Zs[wq][prow][colc]      = a0[r];
      Zs[wq][prow][32 + colc] = a1[r];
      Zs[wq][prow][64 + colc] = a2[r];
    }
    // ---- F2: staged x(s+1) regs -> As (same barrier as Zs) ----
    if (s + 1 < TS) {
#pragma unroll
      for (int k = 0; k < 8; ++k) {
        const int idx = tid + 256 * k;
        *(u32x4*)(&As[(idx >> 6) * XPAD + (idx & 63) * 8]) = xr[k];
      }
    }
    BAR_LGKM();   // Zs ready; As restaged

    // ---- G: epilogue, 3 contiguous cells (row eb, units u0+3ep+q) ----
    float hn[3];
#pragma unroll
    for (int q = 0; q < 3; ++q) {
      const int uu = 3 * ep + q;
      float zi = 0.f, zj = 0.f, zf = 0.f, zo = 0.f;
#pragma unroll
      for (int qq = 0; qq < 4; ++qq) {
        const float4 zp = *(const float4*)(&Zs[qq][eb][uu * 4]);
        zi += zp.x; zj += zp.y; zf += zp.z; zo += zp.w;
      }
      const float ig = 1.f / (1.f + __expf(-(zi + bi[q] + pi[q] * cst[q])));
      const float fg = 1.f / (1.f + __expf(-(zf + bfc[q] + 1.f + pfc[q] * cst[q])));
      const float jt = 1.f - 2.f / (__expf(2.f * (zj + bj[q])) + 1.f);
      const float cn = fg * cst[q] + ig * jt;
      const float og = 1.f / (1.f + __expf(-(zo + bo[q] + po[q] * cn)));
      hn[q] = og * (1.f - 2.f / (__expf(2.f * cn) + 1.f));
      cst[q] = cn;
    }

    // ---- H: publish FIRST (critical path), then out stores (plain, L2-acked) ----
    if (s < TS - 1) {
      const u64 pk = (u64)f2h_bits(hn[0])
                   | ((u64)f2h_bits(hn[1]) << 16)
                   | ((u64)f2h_bits(hn[2]) << 32)
                   | ((u64)(u32)(s + 1) << 48);
      __hip_atomic_store(hdst + eb * 256 + 8 * gg + ep, pk,
                         __ATOMIC_RELAXED, __HIP_MEMORY_SCOPE_AGENT);
    }
    {
      float* op = out + ((size_t)eb * TS + t_in) * 1536 + dir * HU + u0 + 3 * ep;
      op[0] = hn[0]; op[1] = hn[1]; op[2] = hn[2];
    }
  }
}

extern "C" void kernel_launch(void* const* d_in, const int* in_sizes, int n_in,
                              void* d_out, int out_size, void* d_ws, size_t ws_size,
                              hipStream_t stream) {
  const float* x   = (const float*)d_in[0];
  const float* Wfw = (const float*)d_in[1];
  const float* bfw = (const float*)d_in[2];
  const float* pfw = (const float*)d_in[3];
  const float* Wbw = (const float*)d_in[4];
  const float* bbw = (const float*)d_in[5];
  const float* pbw = (const float*)d_in[6];
  float* out = (float*)d_out;

  char* ws = (char*)d_ws;
  unsigned short* xh = (unsigned short*)ws;              // 33,554,432 B
  u64* hb            = (u64*)(ws + 33554432);            //    262,144 B

  lstm_init_k<<<128, 256, 0, stream>>>(hb);
  lstm_xpose_k<<<16384, 256, 0, stream>>>(x, xh);
  lstm_persist_k<<<dim3(2 * NWG), dim3(256), 0, stream>>>(Wfw, bfw, pfw, Wbw, bbw, pbw,
                                                          xh, hb, out);
}

// Round 10
// 5470.651 us; speedup vs baseline: 1.0899x; 1.0899x over previous
//
#include <hip/hip_runtime.h>
#include <stdint.h>

#define TS   1024
#define NB   32
#define DIN  512
#define HU   768
#define NWG  32          // workgroups per direction
#define UPW  24          // hidden units per WG
#define XPAD 520         // x LDS row stride in fp16
#define HPAD 772         // h LDS row stride in fp16 (1544 B rows)
#define SPIN_MAX 16384

typedef _Float16 f16x8 __attribute__((ext_vector_type(8)));
typedef float f32x16 __attribute__((ext_vector_type(16)));
typedef unsigned int u32;
typedef unsigned long long u64;
typedef u32 u32x4 __attribute__((ext_vector_type(4)));

__device__ __forceinline__ u32 f2h_bits(float f) {
  _Float16 h = (_Float16)f;
  return (u32)__builtin_bit_cast(unsigned short, h);
}

// ---- init: zero 2 dirs x 2 slots x 8192 u64 (tag 0 == step-0 ready; replay-safe) ----
__global__ void lstm_init_k(u64* hb) {
  hb[blockIdx.x * 256 + threadIdx.x] = 0ull;   // 128 x 256 = 32768 u64 = 256 KB
}

// ---- transpose + fp16 convert: x[B][T][D] -> xh[T][B][D] ----
__global__ void lstm_xpose_k(const float* __restrict__ x, unsigned short* __restrict__ xh) {
  int idx = blockIdx.x * 256 + threadIdx.x;
  int d4 = idx & 127;
  int t  = (idx >> 7) & 1023;
  int b  = idx >> 17;
  float4 v = *(const float4*)(x + ((size_t)(b * TS + t) * DIN + d4 * 4));
  ushort4 o;
  o.x = (unsigned short)f2h_bits(v.x); o.y = (unsigned short)f2h_bits(v.y);
  o.z = (unsigned short)f2h_bits(v.z); o.w = (unsigned short)f2h_bits(v.w);
  *(ushort4*)(xh + ((size_t)(t * NB + b) * DIN + d4 * 4)) = o;
}

#define BAR_LGKM() do { asm volatile("s_waitcnt lgkmcnt(0)" ::: "memory"); \
  __builtin_amdgcn_sched_barrier(0); __builtin_amdgcn_s_barrier(); \
  __builtin_amdgcn_sched_barrier(0); } while (0)

// ---- persistent bidirectional LSTM scan (64 blocks, tagged-word sync, granular retry) ----
__global__ __launch_bounds__(256, 1) void lstm_persist_k(
    const float* __restrict__ Wfw, const float* __restrict__ bfw, const float* __restrict__ pfw,
    const float* __restrict__ Wbw, const float* __restrict__ bbw, const float* __restrict__ pbw,
    const unsigned short* __restrict__ xh,
    u64* hb, float* __restrict__ out)
{
  __shared__ __align__(16) unsigned short As[NB * XPAD];   // 33,280 B (x tile)
  __shared__ __align__(16) unsigned short Hs[NB * HPAD];   // 49,408 B (h tile, unit-major rows)
  __shared__ __align__(16) float Zs[4][NB][100];           // 51,200 B

  const int tid = threadIdx.x;
  const int dir = (blockIdx.x >= NWG) ? 1 : 0;
  const int gg  = blockIdx.x & (NWG - 1);

  const float* W    = dir ? Wbw : Wfw;
  const float* bias = dir ? bbw : bfw;
  const float* peep = dir ? pbw : pfw;
  u64* hslot = hb + (size_t)dir * 2 * 8192;   // [2 slots][8192 u64]
  const int u0 = gg * UPW;

  const int lane  = tid & 63;
  const int wq    = tid >> 6;      // wave id
  const int colc  = lane & 31;
  const int khalf = lane >> 5;
  const int arow  = colc;          // A-frag row = batch
  const int eb    = tid >> 3;      // epilogue batch row
  const int ep    = tid & 7;       // epilogue phase

  // ---- preload W: 3 col-tiles x 20 K-slices; K-stripe c = 8m + 4*khalf + wq ----
  f16x8 wfr[3][20];
#pragma unroll
  for (int ct = 0; ct < 3; ++ct) {
    const int gcol = (colc & 3) * HU + u0 + 8 * ct + (colc >> 2);
#pragma unroll
    for (int m = 0; m < 20; ++m) {
      const int k0 = (8 * m + 4 * khalf + wq) * 8;
#pragma unroll
      for (int j = 0; j < 8; ++j)
        wfr[ct][m][j] = (_Float16)W[(size_t)(k0 + j) * 3072 + gcol];
    }
  }

  // ---- epilogue constants: 3 contiguous units U = u0 + 3*ep + q ----
  float bi[3], bj[3], bfc[3], bo[3], pi[3], pfc[3], po[3], cst[3];
#pragma unroll
  for (int q = 0; q < 3; ++q) {
    const int U = u0 + 3 * ep + q;
    bi[q] = bias[U]; bj[q] = bias[HU + U]; bfc[q] = bias[2 * HU + U]; bo[q] = bias[3 * HU + U];
    pi[q] = peep[U]; pfc[q] = peep[HU + U]; po[q] = peep[2 * HU + U];
    cst[q] = 0.0f;
  }

  // ---- prologue: x(t0) -> LDS ----
  {
    const unsigned short* x0 = xh + (size_t)(dir ? (TS - 1) : 0) * (NB * DIN);
    u32x4 t[8];
#pragma unroll
    for (int k = 0; k < 8; ++k) t[k] = *(const u32x4*)(x0 + (tid + 256 * k) * 8);
#pragma unroll
    for (int k = 0; k < 8; ++k) {
      const int idx = tid + 256 * k;
      *(u32x4*)(&As[(idx >> 6) * XPAD + (idx & 63) * 8]) = t[k];
    }
  }
  BAR_LGKM();

  // Hs unpack destination base for this thread (producer-major layout decode):
  // word idx0 = 512k + 2*tid -> gg_w = 2k + (tid>>7), eb_w = (tid>>2)&31, ep0 = (2*tid)&7
  // Hs byte = 1544*eb_w + 2*(24*gg_w + 3*ep0) = base0 + 96*k
  const int hsBase0 = 1544 * ((tid >> 2) & 31) + 48 * (tid >> 7) + 6 * ((2 * tid) & 7);

  u32x4 xr[8];   // x prefetch regs for step s+1

  for (int s = 0; s < TS; ++s) {
    const int t_in = dir ? (TS - 1 - s) : s;
    const u32 tag = (u32)s;
    const char* hp = (const char*)(hslot + (size_t)(s & 1) * 8192) + 16 * tid;
    u64* hdst = hslot + (size_t)((s + 1) & 1) * 8192;

    // ---- A: issue tagged h(s) loads (lane-stride 16B, coalesced, MALL) ----
    u32x4 hw[16];
#pragma unroll
    for (int k = 0; k < 16; ++k)
      asm volatile("global_load_dwordx4 %0, %1, off sc0 sc1"
                   : "=v"(hw[k]) : "v"(hp + 4096 * k) : "memory");

    // ---- A2: x(s+1) prefetch (plain cached) — overlaps the same round trip ----
    if (s + 1 < TS) {
      const unsigned short* xnb = xh + (size_t)(dir ? (TS - 2 - s) : (s + 1)) * (NB * DIN);
#pragma unroll
      for (int k = 0; k < 8; ++k) xr[k] = *(const u32x4*)(xnb + (tid + 256 * k) * 8);
    }

    // ---- B: x-tile MFMAs fill part of the latency shadow ----
    f32x16 a0, a1, a2;
#pragma unroll
    for (int r = 0; r < 16; ++r) { a0[r] = 0.f; a1[r] = 0.f; a2[r] = 0.f; }
#pragma unroll
    for (int m = 0; m < 8; ++m) {
      const int c = 8 * m + 4 * khalf + wq;
      const f16x8 av = *(const f16x8*)(&As[arow * XPAD + c * 8]);
      a0 = __builtin_amdgcn_mfma_f32_32x32x16_f16(av, wfr[0][m], a0, 0, 0, 0);
      a1 = __builtin_amdgcn_mfma_f32_32x32x16_f16(av, wfr[1][m], a1, 0, 0, 0);
      a2 = __builtin_amdgcn_mfma_f32_32x32x16_f16(av, wfr[2][m], a2, 0, 0, 0);
    }

    // ---- C: tag check, GRANULAR bounded retry (reissue only stale k's) ----
    {
      u32 freshmask = 0;
      int it = 0;
      while (true) {
        if (it == 0) asm volatile("s_waitcnt vmcnt(8)" ::: "memory");  // h loads done (x may fly)
        else         asm volatile("s_waitcnt vmcnt(0)" ::: "memory");
        __builtin_amdgcn_sched_barrier(0);
        u32 stale = 0;
#pragma unroll
        for (int k = 0; k < 16; ++k) {
          if (!(freshmask & (1u << k))) {
            const u32 badk = ((hw[k][1] >> 16) ^ tag) | ((hw[k][3] >> 16) ^ tag);
            if (__all((int)(badk == 0))) freshmask |= 1u << k;
            else stale |= 1u << k;
          }
        }
        if (stale == 0 || ++it >= SPIN_MAX) break;
        if (it > 2) __builtin_amdgcn_s_sleep(1);
#pragma unroll
        for (int k = 0; k < 16; ++k)
          if (stale & (1u << k))
            asm volatile("global_load_dwordx4 %0, %1, off sc0 sc1"
                         : "=v"(hw[k]) : "v"(hp + 4096 * k) : "memory");
      }
    }

    // ---- D: unpack {3 fp16 + tag}x2 per 16B -> Hs (producer-major decode, 12B/lane) ----
    {
      char* dp0 = (char*)Hs + hsBase0;
#pragma unroll
      for (int k = 0; k < 16; ++k) {
        const u32 xw = hw[k][0], yw = hw[k][1], zw = hw[k][2], ww = hw[k][3];
        char* dp = dp0 + 96 * k;
        *(u32*)(dp)     = xw;
        *(u32*)(dp + 4) = (yw & 0xFFFFu) | (zw << 16);
        *(u32*)(dp + 8) = (zw >> 16) | (ww << 16);
      }
    }
    BAR_LGKM();   // Hs complete; all As x-reads done

    // ---- E: h-tile MFMAs (unit-major Hs rows, stride 1544 B) ----
#pragma unroll
    for (int m = 8; m < 20; ++m) {
      const int c = 8 * m + 4 * khalf + wq;
      const f16x8 av = *(const f16x8*)((char*)Hs + arow * (2 * HPAD) + (c - 64) * 16);
      a0 = __builtin_amdgcn_mfma_f32_32x32x16_f16(av, wfr[0][m], a0, 0, 0, 0);
      a1 = __builtin_amdgcn_mfma_f32_32x32x16_f16(av, wfr[1][m], a1, 0, 0, 0);
      a2 = __builtin_amdgcn_mfma_f32_32x32x16_f16(av, wfr[2][m], a2, 0, 0, 0);
    }

    // ---- F: partial z -> LDS; C/D: col=lane&31, row=(r&3)+8*(r>>2)+4*khalf ----
#pragma unroll
    for (int r = 0; r < 16; ++r) {
      const int prow = (r & 3) + 8 * (r >> 2) + 4 * khalf;
      Zs[wq][prow][colc]      = a0[r];
      Zs[wq][prow][32 + colc] = a1[r];
      Zs[wq][prow][64 + colc] = a2[r];
    }
    // ---- F2: staged x(s+1) regs -> As (same barrier as Zs) ----
    if (s + 1 < TS) {
#pragma unroll
      for (int k = 0; k < 8; ++k) {
        const int idx = tid + 256 * k;
        *(u32x4*)(&As[(idx >> 6) * XPAD + (idx & 63) * 8]) = xr[k];
      }
    }
    BAR_LGKM();   // Zs ready; As restaged

    // ---- G: epilogue, 3 contiguous cells (row eb, units u0+3ep+q) ----
    float hn[3];
#pragma unroll
    for (int q = 0; q < 3; ++q) {
      const int uu = 3 * ep + q;
      float zi = 0.f, zj = 0.f, zf = 0.f, zo = 0.f;
#pragma unroll
      for (int qq = 0; qq < 4; ++qq) {
        const float4 zp = *(const float4*)(&Zs[qq][eb][uu * 4]);
        zi += zp.x; zj += zp.y; zf += zp.z; zo += zp.w;
      }
      const float ig = 1.f / (1.f + __expf(-(zi + bi[q] + pi[q] * cst[q])));
      const float fg = 1.f / (1.f + __expf(-(zf + bfc[q] + 1.f + pfc[q] * cst[q])));
      const float jt = 1.f - 2.f / (__expf(2.f * (zj + bj[q])) + 1.f);
      const float cn = fg * cst[q] + ig * jt;
      const float og = 1.f / (1.f + __expf(-(zo + bo[q] + po[q] * cn)));
      hn[q] = og * (1.f - 2.f / (__expf(2.f * cn) + 1.f));
      cst[q] = cn;
    }

    // ---- H: publish FIRST (producer-major word: idx = gg*256 + tid) ----
    if (s < TS - 1) {
      const u64 pk = (u64)f2h_bits(hn[0])
                   | ((u64)f2h_bits(hn[1]) << 16)
                   | ((u64)f2h_bits(hn[2]) << 32)
                   | ((u64)(u32)(s + 1) << 48);
      __hip_atomic_store(hdst + gg * 256 + tid, pk,
                         __ATOMIC_RELAXED, __HIP_MEMORY_SCOPE_AGENT);
    }
    {
      float* op = out + ((size_t)eb * TS + t_in) * 1536 + dir * HU + u0 + 3 * ep;
      op[0] = hn[0]; op[1] = hn[1]; op[2] = hn[2];
    }
  }
}

extern "C" void kernel_launch(void* const* d_in, const int* in_sizes, int n_in,
                              void* d_out, int out_size, void* d_ws, size_t ws_size,
                              hipStream_t stream) {
  const float* x   = (const float*)d_in[0];
  const float* Wfw = (const float*)d_in[1];
  const float* bfw = (const float*)d_in[2];
  const float* pfw = (const float*)d_in[3];
  const float* Wbw = (const float*)d_in[4];
  const float* bbw = (const float*)d_in[5];
  const float* pbw = (const float*)d_in[6];
  float* out = (float*)d_out;

  char* ws = (char*)d_ws;
  unsigned short* xh = (unsigned short*)ws;              // 33,554,432 B
  u64* hb            = (u64*)(ws + 33554432);            //    262,144 B

  lstm_init_k<<<128, 256, 0, stream>>>(hb);
  lstm_xpose_k<<<16384, 256, 0, stream>>>(x, xh);
  lstm_persist_k<<<dim3(2 * NWG), dim3(256), 0, stream>>>(Wfw, bfw, pfw, Wbw, bbw, pbw,
                                                          xh, hb, out);
}